// Round 19
// baseline (81.669 us; speedup 1.0000x reference)
//
#include <hip/hip_runtime.h>

// Bidirectional NN-MSE via MFMA — R35: identical resubmit of R34 (never ran:
// GPUAcquisitionTimeout; no kernel signal). Re-audit: ma-hazard gap = 3 MFMA
// issues + 28 nops >= 32 OK; mb gap >= 60 OK; operands allocate v0-v31
// (v32-111 clobbered) => frame ~112-120 < 128 cliff; pinned-reg mb pattern
// proven (R18/R32/R33). 4-deep MFMA issue per tile-pair.
// R33 (depth-2 vmcnt pipeline, occupancy preserved) = NULL (80.78 vs 81.2)
// => exposed-memory-latency dead. R31 wall re-derived: 1500 cyc/4-wave-round
// vs 517 MFMA-throughput demand; 16 MFMA x ~94 cyc latency-bound = 1504 —
// EXACT fit. Mechanism: each wave issues only 2 MFMAs before 28 nops + 16
// dependent min3 => matrix pipe ~2 deep/wave, latency-bound at low wave
// count. Explains all nulls (memory overlapped by waves) and QT=4's failure
// (no depth added, cliff paid). Fix: ONE asm per pair issues 4 MFMAs
// back-to-back (a0,a1 x bq0,bq1 -> banks v32-47/48-63/64-79/80-95, C=0),
// then 28-cyc pad, then 16 min3->ma (operands) + 16 min3->mb (PINNED
// v96-111). Nops 56->28/pair; in-flight MFMA ~4/wave (~16/SIMD at 4 waves).
// Plain C++ loads (no mem clobber => compiler prefetches; waves overlap
// waits). SSPLIT=16, inline-0 C kept from R33.
// Predict: loop 14.8 -> 8-10us => dur 80.8 -> 73-77; absmax 0. If null:
// all levers tested-dead -> state structural roofline.
//
//   loss = w * mean_n min_j ||p_n - g_j||^2 + (1-w) * mean_m min_i ||g_m - p_i||^2
//
// d^2 = qq - 2 q.r + rr inside mfma_f32_32x32x16_bf16 (K=16), 2-term bf16
// split per operand (exact bf16xbf16 products; absmax 0 R2-R33).

#define NPTS   16384
#define QBLK   256                // 4 waves x 2 frags x 32 queries (QT=2)
#define QCH    (NPTS / QBLK)      // 64 query chunks
#define SSPLIT 16                 // ref splits
#define RBLK   (NPTS / SSPLIT)    // 1024 refs streamed per block (32 tiles)
#define NB1    (2 * QCH * SSPLIT) // 2048 blocks (8/CU)

typedef __attribute__((ext_vector_type(8)))  __bf16 bf16x8;

union frag16 { __bf16 v[16]; uint4 q[2]; };

// One thread per (role, point): builds A-form (ref) and B-form (query)
// fragments. A-form pre-swizzled in MFMA wave order: uint4 index
// (p>>5)*64 + half*32 + (p&31) -> each wave tile read is one contiguous,
// perfectly-coalesced 1 KB global_load_dwordx4 burst.
__global__ __launch_bounds__(256) void prep_kernel(
    const float* __restrict__ pred, const float* __restrict__ gt,
    uint4* __restrict__ aform, uint4* __restrict__ bform,
    float* __restrict__ out)
{
    const int i = blockIdx.x * 256 + threadIdx.x;   // 0 .. 2*NPTS-1
    if (i == 0) out[0] = 0.0f;
    const int role = (i < NPTS) ? 0 : 1;            // 0=pred, 1=gt
    const int p = i - role * NPTS;
    const float* __restrict__ src = role ? gt : pred;

    const float x = src[p * 3 + 0], y = src[p * 3 + 1], z = src[p * 3 + 2];
    const float nn = x * x + y * y + z * z;
    const __bf16 xh = (__bf16)x, yh = (__bf16)y, zh = (__bf16)z;
    const __bf16 xl = (__bf16)(x - (float)xh);
    const __bf16 yl = (__bf16)(y - (float)yh);
    const __bf16 zl = (__bf16)(z - (float)zh);
    const __bf16 nh = (__bf16)nn;
    const __bf16 nl = (__bf16)(nn - (float)nh);
    const __bf16 one = (__bf16)1.0f;

    frag16 A;
    A.v[0]  = (__bf16)(-2.0f * (float)xh); A.v[1]  = A.v[0];
    A.v[2]  = (__bf16)(-2.0f * (float)xl); A.v[3]  = A.v[2];
    A.v[4]  = (__bf16)(-2.0f * (float)yh); A.v[5]  = A.v[4];
    A.v[6]  = (__bf16)(-2.0f * (float)yl); A.v[7]  = A.v[6];
    A.v[8]  = (__bf16)(-2.0f * (float)zh); A.v[9]  = A.v[8];
    A.v[10] = (__bf16)(-2.0f * (float)zl); A.v[11] = A.v[10];
    A.v[12] = nh;  A.v[13] = nl;  A.v[14] = one;  A.v[15] = one;

    frag16 B;
    B.v[0] = xh;  B.v[1]  = xl;  B.v[2]  = xh;  B.v[3]  = xl;
    B.v[4] = yh;  B.v[5]  = yl;  B.v[6]  = yh;  B.v[7]  = yl;
    B.v[8] = zh;  B.v[9]  = zl;  B.v[10] = zh;  B.v[11] = zl;
    B.v[12] = one; B.v[13] = one; B.v[14] = nh;  B.v[15] = nl;

    uint4* da = aform + (size_t)role * (NPTS * 2)
              + ((p >> 5) * 64 + (p & 31));
    da[0]  = A.q[0];        // half 0 (k=0..7)  at +0
    da[32] = A.q[1];        // half 1 (k=8..15) at +32
    uint4* db = bform + (size_t)role * (NPTS * 2) + p * 2;
    db[0] = B.q[0];
    db[1] = B.q[1];
}

// 4-deep MFMA block: all 4 MFMAs of the tile-pair issue back-to-back into
// four pinned banks, THEN the hazard pad, THEN both min3 sets. ma via
// "+v" operands; mb accumulates in PINNED v96-111 (physical-reg invariant
// across invocations, maintained by init/readout asms).
#define MMB4(A0, A1, BQ0, BQ1, M)                                           \
    asm volatile(                                                           \
        "v_mfma_f32_32x32x16_bf16 v[32:47], %[a0], %[b0], 0\n\t"            \
        "v_mfma_f32_32x32x16_bf16 v[48:63], %[a1], %[b0], 0\n\t"            \
        "v_mfma_f32_32x32x16_bf16 v[64:79], %[a0], %[b1], 0\n\t"            \
        "v_mfma_f32_32x32x16_bf16 v[80:95], %[a1], %[b1], 0\n\t"            \
        "s_nop 7\n\ts_nop 7\n\ts_nop 7\n\ts_nop 7\n\t"                      \
        "v_min3_f32 %[M0],  %[M0],  v32, v48\n\t"                           \
        "v_min3_f32 %[M1],  %[M1],  v33, v49\n\t"                           \
        "v_min3_f32 %[M2],  %[M2],  v34, v50\n\t"                           \
        "v_min3_f32 %[M3],  %[M3],  v35, v51\n\t"                           \
        "v_min3_f32 %[M4],  %[M4],  v36, v52\n\t"                           \
        "v_min3_f32 %[M5],  %[M5],  v37, v53\n\t"                           \
        "v_min3_f32 %[M6],  %[M6],  v38, v54\n\t"                           \
        "v_min3_f32 %[M7],  %[M7],  v39, v55\n\t"                           \
        "v_min3_f32 %[M8],  %[M8],  v40, v56\n\t"                           \
        "v_min3_f32 %[M9],  %[M9],  v41, v57\n\t"                           \
        "v_min3_f32 %[M10], %[M10], v42, v58\n\t"                           \
        "v_min3_f32 %[M11], %[M11], v43, v59\n\t"                           \
        "v_min3_f32 %[M12], %[M12], v44, v60\n\t"                           \
        "v_min3_f32 %[M13], %[M13], v45, v61\n\t"                           \
        "v_min3_f32 %[M14], %[M14], v46, v62\n\t"                           \
        "v_min3_f32 %[M15], %[M15], v47, v63\n\t"                           \
        "v_min3_f32 v96,  v96,  v64, v80\n\t"                               \
        "v_min3_f32 v97,  v97,  v65, v81\n\t"                               \
        "v_min3_f32 v98,  v98,  v66, v82\n\t"                               \
        "v_min3_f32 v99,  v99,  v67, v83\n\t"                               \
        "v_min3_f32 v100, v100, v68, v84\n\t"                               \
        "v_min3_f32 v101, v101, v69, v85\n\t"                               \
        "v_min3_f32 v102, v102, v70, v86\n\t"                               \
        "v_min3_f32 v103, v103, v71, v87\n\t"                               \
        "v_min3_f32 v104, v104, v72, v88\n\t"                               \
        "v_min3_f32 v105, v105, v73, v89\n\t"                               \
        "v_min3_f32 v106, v106, v74, v90\n\t"                               \
        "v_min3_f32 v107, v107, v75, v91\n\t"                               \
        "v_min3_f32 v108, v108, v76, v92\n\t"                               \
        "v_min3_f32 v109, v109, v77, v93\n\t"                               \
        "v_min3_f32 v110, v110, v78, v94\n\t"                               \
        "v_min3_f32 v111, v111, v79, v95"                                   \
        : [M0] "+v"(M[0]),  [M1] "+v"(M[1]),  [M2] "+v"(M[2]),              \
          [M3] "+v"(M[3]),  [M4] "+v"(M[4]),  [M5] "+v"(M[5]),              \
          [M6] "+v"(M[6]),  [M7] "+v"(M[7]),  [M8] "+v"(M[8]),              \
          [M9] "+v"(M[9]),  [M10] "+v"(M[10]), [M11] "+v"(M[11]),           \
          [M12] "+v"(M[12]), [M13] "+v"(M[13]), [M14] "+v"(M[14]),          \
          [M15] "+v"(M[15])                                                 \
        : [a0] "v"(A0), [a1] "v"(A1), [b0] "v"(BQ0), [b1] "v"(BQ1)          \
        : "v32", "v33", "v34", "v35", "v36", "v37", "v38", "v39",           \
          "v40", "v41", "v42", "v43", "v44", "v45", "v46", "v47",           \
          "v48", "v49", "v50", "v51", "v52", "v53", "v54", "v55",           \
          "v56", "v57", "v58", "v59", "v60", "v61", "v62", "v63",           \
          "v64", "v65", "v66", "v67", "v68", "v69", "v70", "v71",           \
          "v72", "v73", "v74", "v75", "v76", "v77", "v78", "v79",           \
          "v80", "v81", "v82", "v83", "v84", "v85", "v86", "v87",           \
          "v88", "v89", "v90", "v91", "v92", "v93", "v94", "v95",           \
          "v96", "v97", "v98", "v99", "v100", "v101", "v102", "v103",       \
          "v104", "v105", "v106", "v107", "v108", "v109", "v110", "v111")

__global__ __launch_bounds__(256) void nn_part_kernel(
    const uint4* __restrict__ aform, const uint4* __restrict__ bform,
    float* __restrict__ partial)
{
    const int bx   = blockIdx.x;           // 0..NB1-1
    const int dir  = bx >> 10;             // 0: Q=pred,R=gt ; 1: Q=gt,R=pred
    const int qc   = (bx >> 4) & 63;       // 0..63
    const int s    = bx & 15;              // 0..15
    const int tid  = threadIdx.x;
    const int lane = tid & 63;
    const int wave = tid >> 6;
    const int lid  = lane & 31;
    const int half = lane >> 5;

    // dir 0: queries=pred(role 0), refs=gt(role 1); dir 1 swapped
    const uint4* __restrict__ Aref = aform + (size_t)(dir ? 0 : 1) * (NPTS * 2);
    const uint4* __restrict__ Bqry = bform + (size_t)(dir ? 1 : 0) * (NPTS * 2);

    // ---- two query B-fragments per wave (prebuilt, 16 B/lane) ----
    const int qbase = qc * QBLK + wave * 64;
    const bf16x8 bq0 = __builtin_bit_cast(bf16x8, Bqry[(qbase + lid) * 2 + half]);
    const bf16x8 bq1 = __builtin_bit_cast(bf16x8, Bqry[(qbase + 32 + lid) * 2 + half]);

    float ma[16];
#pragma unroll
    for (int k = 0; k < 16; ++k) ma[k] = 3.4e38f;

    // mb accumulators: pinned v96-111, init to +FLT_MAX.
    asm volatile(
        "v_mov_b32 v96,  0x7F7FFFFF\n\tv_mov_b32 v97,  0x7F7FFFFF\n\t"
        "v_mov_b32 v98,  0x7F7FFFFF\n\tv_mov_b32 v99,  0x7F7FFFFF\n\t"
        "v_mov_b32 v100, 0x7F7FFFFF\n\tv_mov_b32 v101, 0x7F7FFFFF\n\t"
        "v_mov_b32 v102, 0x7F7FFFFF\n\tv_mov_b32 v103, 0x7F7FFFFF\n\t"
        "v_mov_b32 v104, 0x7F7FFFFF\n\tv_mov_b32 v105, 0x7F7FFFFF\n\t"
        "v_mov_b32 v106, 0x7F7FFFFF\n\tv_mov_b32 v107, 0x7F7FFFFF\n\t"
        "v_mov_b32 v108, 0x7F7FFFFF\n\tv_mov_b32 v109, 0x7F7FFFFF\n\t"
        "v_mov_b32 v110, 0x7F7FFFFF\n\tv_mov_b32 v111, 0x7F7FFFFF"
        ::: "v96", "v97", "v98", "v99", "v100", "v101", "v102", "v103",
            "v104", "v105", "v106", "v107", "v108", "v109", "v110", "v111");

    // ---- hot loop: one MMB4 per tile-pair (4 MFMAs back-to-back) ----
    const uint4* gp = Aref + (size_t)s * (RBLK * 2) + half * 32 + lid;
#pragma unroll 2
    for (int t = 0; t < RBLK / 32; t += 2) {
        const bf16x8 a0 = __builtin_bit_cast(bf16x8, gp[t * 64]);
        const bf16x8 a1 = __builtin_bit_cast(bf16x8, gp[t * 64 + 64]);
        MMB4(a0, a1, bq0, bq1, ma);
    }

    // Read out mb from pinned v96-111.
    float mb[16];
    asm volatile(
        "v_mov_b32 %0,  v96\n\tv_mov_b32 %1,  v97\n\t"
        "v_mov_b32 %2,  v98\n\tv_mov_b32 %3,  v99\n\t"
        "v_mov_b32 %4,  v100\n\tv_mov_b32 %5,  v101\n\t"
        "v_mov_b32 %6,  v102\n\tv_mov_b32 %7,  v103\n\t"
        "v_mov_b32 %8,  v104\n\tv_mov_b32 %9,  v105\n\t"
        "v_mov_b32 %10, v106\n\tv_mov_b32 %11, v107\n\t"
        "v_mov_b32 %12, v108\n\tv_mov_b32 %13, v109\n\t"
        "v_mov_b32 %14, v110\n\tv_mov_b32 %15, v111"
        : "=v"(mb[0]), "=v"(mb[1]), "=v"(mb[2]), "=v"(mb[3]),
          "=v"(mb[4]), "=v"(mb[5]), "=v"(mb[6]), "=v"(mb[7]),
          "=v"(mb[8]), "=v"(mb[9]), "=v"(mb[10]), "=v"(mb[11]),
          "=v"(mb[12]), "=v"(mb[13]), "=v"(mb[14]), "=v"(mb[15])
        :
        : "v96", "v97", "v98", "v99", "v100", "v101", "v102", "v103",
          "v104", "v105", "v106", "v107", "v108", "v109", "v110", "v111");

    // ---- tail: in-lane trees + one shuffle each, plain coalesced store ----
    float* pout = partial + ((size_t)((dir * QCH + qc) * SSPLIT + s)) * QBLK
                + wave * 64;
    {
        float a = fminf(fminf(ma[0], ma[1]), fminf(ma[2], ma[3]));
        float b = fminf(fminf(ma[4], ma[5]), fminf(ma[6], ma[7]));
        float c = fminf(fminf(ma[8], ma[9]), fminf(ma[10], ma[11]));
        float d = fminf(fminf(ma[12], ma[13]), fminf(ma[14], ma[15]));
        float v = fminf(fminf(a, b), fminf(c, d));
        v = fminf(v, __shfl_xor(v, 32));
        if (half == 0) pout[lid] = v;
    }
    {
        float a = fminf(fminf(mb[0], mb[1]), fminf(mb[2], mb[3]));
        float b = fminf(fminf(mb[4], mb[5]), fminf(mb[6], mb[7]));
        float c = fminf(fminf(mb[8], mb[9]), fminf(mb[10], mb[11]));
        float d = fminf(fminf(mb[12], mb[13]), fminf(mb[14], mb[15]));
        float v = fminf(fminf(a, b), fminf(c, d));
        v = fminf(v, __shfl_xor(v, 32));
        if (half == 0) pout[32 + lid] = v;
    }
}

// Combine: min over the SSPLIT ref-splits per query, weighted sum into out.
__global__ __launch_bounds__(256) void nn_combine_kernel(
    const float* __restrict__ partial, const float* __restrict__ weight,
    float* __restrict__ out)
{
    const int b   = blockIdx.x;        // 0..127 : dir = b>>6, qc = b&63
    const int dir = b >> 6;
    const int qc  = b & 63;
    const int t   = threadIdx.x;

    const float* p = partial + ((size_t)((dir * QCH + qc) * SSPLIT)) * QBLK;
    float v = p[t];
#pragma unroll
    for (int s = 1; s < SSPLIT; ++s)
        v = fminf(v, p[(size_t)s * QBLK + t]);

    for (int off = 32; off; off >>= 1) v += __shfl_down(v, off);
    __shared__ float ws[4];
    if ((t & 63) == 0) ws[t >> 6] = v;
    __syncthreads();
    if (t == 0) {
        const float sum = ws[0] + ws[1] + ws[2] + ws[3];
        const float wgt = weight[0];
        const float scale = (dir ? (1.0f - wgt) : wgt) / (3.0f * (float)NPTS);
        atomicAdd(out, sum * scale);
    }
}

extern "C" void kernel_launch(void* const* d_in, const int* in_sizes, int n_in,
                              void* d_out, int out_size, void* d_ws, size_t ws_size,
                              hipStream_t stream) {
    const float* pred   = (const float*)d_in[0];
    const float* gt     = (const float*)d_in[1];
    const float* weight = (const float*)d_in[2];

    // ws: [partial 2 MB][aform 1 MB][bform 1 MB]
    float* partial = (float*)d_ws;                       // 2*QCH*SSPLIT*QBLK f32
    uint4* aform = (uint4*)((char*)d_ws + (size_t)2 * QCH * SSPLIT * QBLK * 4);
    uint4* bform = aform + (size_t)2 * NPTS * 2;

    prep_kernel<<<2 * NPTS / 256, 256, 0, stream>>>(pred, gt, aform, bform,
                                                    (float*)d_out);
    nn_part_kernel<<<NB1, 256, 0, stream>>>(aform, bform, partial);
    nn_combine_kernel<<<2 * QCH, 256, 0, stream>>>(partial, weight, (float*)d_out);
}

// Round 20
// 80.756 us; speedup vs baseline: 1.0113x; 1.0113x over previous
//
#include <hip/hip_runtime.h>

// Bidirectional NN-MSE via MFMA — R36: bank PING-PONG — min3 consumes the
// PREVIOUS unit's MFMA banks, never the just-issued ones.
// R35 (4-deep issue, nops halved) = NULL. Units fix: one 32x32x16 MFMA =
// 32.3 cyc per SIMD (2495TF/1024 SIMD/2.4GHz; the 8.07 figure is per-CU),
// so matrix demand/pass = 6.9us — exactly the 35% MfmaUtil measured at the
// 14.8us pass. Every prior variant kept the in-wave completion-wait (min3
// reads the MFMAs issued moments before: ~130 cyc wait per 4 MFMAs). This
// version: [MFMA a*bq0->A(v32-63)][min3 B->mb] [MFMA a*bq1->B(v64-95)]
// [min3 A->ma] — each min3 reads banks written >=40 real cycles earlier
// (hazard met by interleave; ZERO s_nops steady-state). Wave cadence ~92c
// per 4 MFMAs vs 129c matrix demand => ONE wave saturates the pipe solo —
// robust to convoy/occupancy. Prologue: B=+INF (first min3-B harmless);
// epilogue drains last B. 2 asm blocks/iter (19 operands each); pinned
// v32-95 only; frame ~124 <= 128 => 4 waves/SIMD preserved.
// Predict: MfmaUtil 35->70-90%, loop 14.8->~8us => dur 73-76; absmax 0.
// PRE-COMMIT: null => binder is sub-issue-level (RF-port/operand-fetch
// contention, unfixable at this mix) => next round states the structural
// roofline and stops.
//
//   loss = w * mean_n min_j ||p_n - g_j||^2 + (1-w) * mean_m min_i ||g_m - p_i||^2
//
// d^2 = qq - 2 q.r + rr inside mfma_f32_32x32x16_bf16 (K=16), 2-term bf16
// split per operand (exact bf16xbf16 products; absmax 0 R2-R35).

#define NPTS   16384
#define QBLK   256                // 4 waves x 2 frags x 32 queries (QT=2)
#define QCH    (NPTS / QBLK)      // 64 query chunks
#define SSPLIT 16                 // ref splits
#define RBLK   (NPTS / SSPLIT)    // 1024 refs streamed per block (32 tiles)
#define NB1    (2 * QCH * SSPLIT) // 2048 blocks (8/CU)

typedef __attribute__((ext_vector_type(8)))  __bf16 bf16x8;

union frag16 { __bf16 v[16]; uint4 q[2]; };

// One thread per (role, point): builds A-form (ref) and B-form (query)
// fragments. A-form pre-swizzled in MFMA wave order: uint4 index
// (p>>5)*64 + half*32 + (p&31) -> each wave tile read is one contiguous,
// perfectly-coalesced 1 KB global_load_dwordx4 burst.
__global__ __launch_bounds__(256) void prep_kernel(
    const float* __restrict__ pred, const float* __restrict__ gt,
    uint4* __restrict__ aform, uint4* __restrict__ bform,
    float* __restrict__ out)
{
    const int i = blockIdx.x * 256 + threadIdx.x;   // 0 .. 2*NPTS-1
    if (i == 0) out[0] = 0.0f;
    const int role = (i < NPTS) ? 0 : 1;            // 0=pred, 1=gt
    const int p = i - role * NPTS;
    const float* __restrict__ src = role ? gt : pred;

    const float x = src[p * 3 + 0], y = src[p * 3 + 1], z = src[p * 3 + 2];
    const float nn = x * x + y * y + z * z;
    const __bf16 xh = (__bf16)x, yh = (__bf16)y, zh = (__bf16)z;
    const __bf16 xl = (__bf16)(x - (float)xh);
    const __bf16 yl = (__bf16)(y - (float)yh);
    const __bf16 zl = (__bf16)(z - (float)zh);
    const __bf16 nh = (__bf16)nn;
    const __bf16 nl = (__bf16)(nn - (float)nh);
    const __bf16 one = (__bf16)1.0f;

    frag16 A;
    A.v[0]  = (__bf16)(-2.0f * (float)xh); A.v[1]  = A.v[0];
    A.v[2]  = (__bf16)(-2.0f * (float)xl); A.v[3]  = A.v[2];
    A.v[4]  = (__bf16)(-2.0f * (float)yh); A.v[5]  = A.v[4];
    A.v[6]  = (__bf16)(-2.0f * (float)yl); A.v[7]  = A.v[6];
    A.v[8]  = (__bf16)(-2.0f * (float)zh); A.v[9]  = A.v[8];
    A.v[10] = (__bf16)(-2.0f * (float)zl); A.v[11] = A.v[10];
    A.v[12] = nh;  A.v[13] = nl;  A.v[14] = one;  A.v[15] = one;

    frag16 B;
    B.v[0] = xh;  B.v[1]  = xl;  B.v[2]  = xh;  B.v[3]  = xl;
    B.v[4] = yh;  B.v[5]  = yl;  B.v[6]  = yh;  B.v[7]  = yl;
    B.v[8] = zh;  B.v[9]  = zl;  B.v[10] = zh;  B.v[11] = zl;
    B.v[12] = one; B.v[13] = one; B.v[14] = nh;  B.v[15] = nl;

    uint4* da = aform + (size_t)role * (NPTS * 2)
              + ((p >> 5) * 64 + (p & 31));
    da[0]  = A.q[0];        // half 0 (k=0..7)  at +0
    da[32] = A.q[1];        // half 1 (k=8..15) at +32
    uint4* db = bform + (size_t)role * (NPTS * 2) + p * 2;
    db[0] = B.q[0];
    db[1] = B.q[1];
}

// Phase 1: issue (a0,a1)xBQ0 into bank A (v32-63), reduce bank B (previous
// unit's bq1 results) into mb. min3 reads banks written >=40 cyc earlier.
#define MFMA_A_MIN_B(A0, A1, BQ0, MB)                                       \
    asm volatile(                                                           \
        "v_mfma_f32_32x32x16_bf16 v[32:47], %[a0], %[b], 0\n\t"             \
        "v_mfma_f32_32x32x16_bf16 v[48:63], %[a1], %[b], 0\n\t"             \
        "v_min3_f32 %[M0],  %[M0],  v64, v80\n\t"                           \
        "v_min3_f32 %[M1],  %[M1],  v65, v81\n\t"                           \
        "v_min3_f32 %[M2],  %[M2],  v66, v82\n\t"                           \
        "v_min3_f32 %[M3],  %[M3],  v67, v83\n\t"                           \
        "v_min3_f32 %[M4],  %[M4],  v68, v84\n\t"                           \
        "v_min3_f32 %[M5],  %[M5],  v69, v85\n\t"                           \
        "v_min3_f32 %[M6],  %[M6],  v70, v86\n\t"                           \
        "v_min3_f32 %[M7],  %[M7],  v71, v87\n\t"                           \
        "v_min3_f32 %[M8],  %[M8],  v72, v88\n\t"                           \
        "v_min3_f32 %[M9],  %[M9],  v73, v89\n\t"                           \
        "v_min3_f32 %[M10], %[M10], v74, v90\n\t"                           \
        "v_min3_f32 %[M11], %[M11], v75, v91\n\t"                           \
        "v_min3_f32 %[M12], %[M12], v76, v92\n\t"                           \
        "v_min3_f32 %[M13], %[M13], v77, v93\n\t"                           \
        "v_min3_f32 %[M14], %[M14], v78, v94\n\t"                           \
        "v_min3_f32 %[M15], %[M15], v79, v95"                               \
        : [M0] "+v"(MB[0]),  [M1] "+v"(MB[1]),  [M2] "+v"(MB[2]),           \
          [M3] "+v"(MB[3]),  [M4] "+v"(MB[4]),  [M5] "+v"(MB[5]),           \
          [M6] "+v"(MB[6]),  [M7] "+v"(MB[7]),  [M8] "+v"(MB[8]),           \
          [M9] "+v"(MB[9]),  [M10] "+v"(MB[10]), [M11] "+v"(MB[11]),        \
          [M12] "+v"(MB[12]), [M13] "+v"(MB[13]), [M14] "+v"(MB[14]),       \
          [M15] "+v"(MB[15])                                                \
        : [a0] "v"(A0), [a1] "v"(A1), [b] "v"(BQ0)                          \
        : "v32", "v33", "v34", "v35", "v36", "v37", "v38", "v39",           \
          "v40", "v41", "v42", "v43", "v44", "v45", "v46", "v47",           \
          "v48", "v49", "v50", "v51", "v52", "v53", "v54", "v55",           \
          "v56", "v57", "v58", "v59", "v60", "v61", "v62", "v63",           \
          "v64", "v65", "v66", "v67", "v68", "v69", "v70", "v71",           \
          "v72", "v73", "v74", "v75", "v76", "v77", "v78", "v79",           \
          "v80", "v81", "v82", "v83", "v84", "v85", "v86", "v87",           \
          "v88", "v89", "v90", "v91", "v92", "v93", "v94", "v95")

// Phase 2: issue (a0,a1)xBQ1 into bank B (v64-95), reduce bank A (this
// unit's bq0 results, written one phase ago: gap = 16 min3 + 2 issue >= 40).
#define MFMA_B_MIN_A(A0, A1, BQ1, MA)                                       \
    asm volatile(                                                           \
        "v_mfma_f32_32x32x16_bf16 v[64:79], %[a0], %[b], 0\n\t"             \
        "v_mfma_f32_32x32x16_bf16 v[80:95], %[a1], %[b], 0\n\t"             \
        "v_min3_f32 %[M0],  %[M0],  v32, v48\n\t"                           \
        "v_min3_f32 %[M1],  %[M1],  v33, v49\n\t"                           \
        "v_min3_f32 %[M2],  %[M2],  v34, v50\n\t"                           \
        "v_min3_f32 %[M3],  %[M3],  v35, v51\n\t"                           \
        "v_min3_f32 %[M4],  %[M4],  v36, v52\n\t"                           \
        "v_min3_f32 %[M5],  %[M5],  v37, v53\n\t"                           \
        "v_min3_f32 %[M6],  %[M6],  v38, v54\n\t"                           \
        "v_min3_f32 %[M7],  %[M7],  v39, v55\n\t"                           \
        "v_min3_f32 %[M8],  %[M8],  v40, v56\n\t"                           \
        "v_min3_f32 %[M9],  %[M9],  v41, v57\n\t"                           \
        "v_min3_f32 %[M10], %[M10], v42, v58\n\t"                           \
        "v_min3_f32 %[M11], %[M11], v43, v59\n\t"                           \
        "v_min3_f32 %[M12], %[M12], v44, v60\n\t"                           \
        "v_min3_f32 %[M13], %[M13], v45, v61\n\t"                           \
        "v_min3_f32 %[M14], %[M14], v46, v62\n\t"                           \
        "v_min3_f32 %[M15], %[M15], v47, v63"                               \
        : [M0] "+v"(MA[0]),  [M1] "+v"(MA[1]),  [M2] "+v"(MA[2]),           \
          [M3] "+v"(MA[3]),  [M4] "+v"(MA[4]),  [M5] "+v"(MA[5]),           \
          [M6] "+v"(MA[6]),  [M7] "+v"(MA[7]),  [M8] "+v"(MA[8]),           \
          [M9] "+v"(MA[9]),  [M10] "+v"(MA[10]), [M11] "+v"(MA[11]),        \
          [M12] "+v"(MA[12]), [M13] "+v"(MA[13]), [M14] "+v"(MA[14]),       \
          [M15] "+v"(MA[15])                                                \
        : [a0] "v"(A0), [a1] "v"(A1), [b] "v"(BQ1)                          \
        : "v32", "v33", "v34", "v35", "v36", "v37", "v38", "v39",           \
          "v40", "v41", "v42", "v43", "v44", "v45", "v46", "v47",           \
          "v48", "v49", "v50", "v51", "v52", "v53", "v54", "v55",           \
          "v56", "v57", "v58", "v59", "v60", "v61", "v62", "v63",           \
          "v64", "v65", "v66", "v67", "v68", "v69", "v70", "v71",           \
          "v72", "v73", "v74", "v75", "v76", "v77", "v78", "v79",           \
          "v80", "v81", "v82", "v83", "v84", "v85", "v86", "v87",           \
          "v88", "v89", "v90", "v91", "v92", "v93", "v94", "v95")

__global__ __launch_bounds__(256) void nn_part_kernel(
    const uint4* __restrict__ aform, const uint4* __restrict__ bform,
    float* __restrict__ partial)
{
    const int bx   = blockIdx.x;           // 0..NB1-1
    const int dir  = bx >> 10;             // 0: Q=pred,R=gt ; 1: Q=gt,R=pred
    const int qc   = (bx >> 4) & 63;       // 0..63
    const int s    = bx & 15;              // 0..15
    const int tid  = threadIdx.x;
    const int lane = tid & 63;
    const int wave = tid >> 6;
    const int lid  = lane & 31;
    const int half = lane >> 5;

    // dir 0: queries=pred(role 0), refs=gt(role 1); dir 1 swapped
    const uint4* __restrict__ Aref = aform + (size_t)(dir ? 0 : 1) * (NPTS * 2);
    const uint4* __restrict__ Bqry = bform + (size_t)(dir ? 1 : 0) * (NPTS * 2);

    // ---- two query B-fragments per wave (prebuilt, 16 B/lane) ----
    const int qbase = qc * QBLK + wave * 64;
    const bf16x8 bq0 = __builtin_bit_cast(bf16x8, Bqry[(qbase + lid) * 2 + half]);
    const bf16x8 bq1 = __builtin_bit_cast(bf16x8, Bqry[(qbase + 32 + lid) * 2 + half]);

    float ma[16], mb[16];
#pragma unroll
    for (int k = 0; k < 16; ++k) { ma[k] = 3.4e38f; mb[k] = 3.4e38f; }

    // Init bank B (v64-95) to +FLT_MAX so iteration 0's min3-B is harmless.
    asm volatile(
        "v_mov_b32 v64, 0x7F7FFFFF\n\tv_mov_b32 v65, 0x7F7FFFFF\n\t"
        "v_mov_b32 v66, 0x7F7FFFFF\n\tv_mov_b32 v67, 0x7F7FFFFF\n\t"
        "v_mov_b32 v68, 0x7F7FFFFF\n\tv_mov_b32 v69, 0x7F7FFFFF\n\t"
        "v_mov_b32 v70, 0x7F7FFFFF\n\tv_mov_b32 v71, 0x7F7FFFFF\n\t"
        "v_mov_b32 v72, 0x7F7FFFFF\n\tv_mov_b32 v73, 0x7F7FFFFF\n\t"
        "v_mov_b32 v74, 0x7F7FFFFF\n\tv_mov_b32 v75, 0x7F7FFFFF\n\t"
        "v_mov_b32 v76, 0x7F7FFFFF\n\tv_mov_b32 v77, 0x7F7FFFFF\n\t"
        "v_mov_b32 v78, 0x7F7FFFFF\n\tv_mov_b32 v79, 0x7F7FFFFF\n\t"
        "v_mov_b32 v80, 0x7F7FFFFF\n\tv_mov_b32 v81, 0x7F7FFFFF\n\t"
        "v_mov_b32 v82, 0x7F7FFFFF\n\tv_mov_b32 v83, 0x7F7FFFFF\n\t"
        "v_mov_b32 v84, 0x7F7FFFFF\n\tv_mov_b32 v85, 0x7F7FFFFF\n\t"
        "v_mov_b32 v86, 0x7F7FFFFF\n\tv_mov_b32 v87, 0x7F7FFFFF\n\t"
        "v_mov_b32 v88, 0x7F7FFFFF\n\tv_mov_b32 v89, 0x7F7FFFFF\n\t"
        "v_mov_b32 v90, 0x7F7FFFFF\n\tv_mov_b32 v91, 0x7F7FFFFF\n\t"
        "v_mov_b32 v92, 0x7F7FFFFF\n\tv_mov_b32 v93, 0x7F7FFFFF\n\t"
        "v_mov_b32 v94, 0x7F7FFFFF\n\tv_mov_b32 v95, 0x7F7FFFFF"
        ::: "v64", "v65", "v66", "v67", "v68", "v69", "v70", "v71",
            "v72", "v73", "v74", "v75", "v76", "v77", "v78", "v79",
            "v80", "v81", "v82", "v83", "v84", "v85", "v86", "v87",
            "v88", "v89", "v90", "v91", "v92", "v93", "v94", "v95");

    // ---- hot loop: ping-pong; min3 never waits on a just-issued MFMA ----
    const uint4* gp = Aref + (size_t)s * (RBLK * 2) + half * 32 + lid;
#pragma unroll 2
    for (int t = 0; t < RBLK / 32; t += 2) {
        const bf16x8 a0 = __builtin_bit_cast(bf16x8, gp[t * 64]);
        const bf16x8 a1 = __builtin_bit_cast(bf16x8, gp[t * 64 + 64]);
        MFMA_A_MIN_B(a0, a1, bq0, mb);   // A <- a x bq0 ; mb <- min(B_prev)
        MFMA_B_MIN_A(a0, a1, bq1, ma);   // B <- a x bq1 ; ma <- min(A)
    }

    // Epilogue: drain the final B bank (last tile-pair's bq1 results).
    asm volatile(
        "s_nop 7\n\ts_nop 7\n\ts_nop 7\n\ts_nop 7\n\t"
        "v_min3_f32 %[M0],  %[M0],  v64, v80\n\t"
        "v_min3_f32 %[M1],  %[M1],  v65, v81\n\t"
        "v_min3_f32 %[M2],  %[M2],  v66, v82\n\t"
        "v_min3_f32 %[M3],  %[M3],  v67, v83\n\t"
        "v_min3_f32 %[M4],  %[M4],  v68, v84\n\t"
        "v_min3_f32 %[M5],  %[M5],  v69, v85\n\t"
        "v_min3_f32 %[M6],  %[M6],  v70, v86\n\t"
        "v_min3_f32 %[M7],  %[M7],  v71, v87\n\t"
        "v_min3_f32 %[M8],  %[M8],  v72, v88\n\t"
        "v_min3_f32 %[M9],  %[M9],  v73, v89\n\t"
        "v_min3_f32 %[M10], %[M10], v74, v90\n\t"
        "v_min3_f32 %[M11], %[M11], v75, v91\n\t"
        "v_min3_f32 %[M12], %[M12], v76, v92\n\t"
        "v_min3_f32 %[M13], %[M13], v77, v93\n\t"
        "v_min3_f32 %[M14], %[M14], v78, v94\n\t"
        "v_min3_f32 %[M15], %[M15], v79, v95"
        : [M0] "+v"(mb[0]),  [M1] "+v"(mb[1]),  [M2] "+v"(mb[2]),
          [M3] "+v"(mb[3]),  [M4] "+v"(mb[4]),  [M5] "+v"(mb[5]),
          [M6] "+v"(mb[6]),  [M7] "+v"(mb[7]),  [M8] "+v"(mb[8]),
          [M9] "+v"(mb[9]),  [M10] "+v"(mb[10]), [M11] "+v"(mb[11]),
          [M12] "+v"(mb[12]), [M13] "+v"(mb[13]), [M14] "+v"(mb[14]),
          [M15] "+v"(mb[15])
        :
        : "v64", "v65", "v66", "v67", "v68", "v69", "v70", "v71",
          "v72", "v73", "v74", "v75", "v76", "v77", "v78", "v79",
          "v80", "v81", "v82", "v83", "v84", "v85", "v86", "v87",
          "v88", "v89", "v90", "v91", "v92", "v93", "v94", "v95");

    // ---- tail: in-lane trees + one shuffle each, plain coalesced store ----
    float* pout = partial + ((size_t)((dir * QCH + qc) * SSPLIT + s)) * QBLK
                + wave * 64;
    {
        float a = fminf(fminf(ma[0], ma[1]), fminf(ma[2], ma[3]));
        float b = fminf(fminf(ma[4], ma[5]), fminf(ma[6], ma[7]));
        float c = fminf(fminf(ma[8], ma[9]), fminf(ma[10], ma[11]));
        float d = fminf(fminf(ma[12], ma[13]), fminf(ma[14], ma[15]));
        float v = fminf(fminf(a, b), fminf(c, d));
        v = fminf(v, __shfl_xor(v, 32));
        if (half == 0) pout[lid] = v;
    }
    {
        float a = fminf(fminf(mb[0], mb[1]), fminf(mb[2], mb[3]));
        float b = fminf(fminf(mb[4], mb[5]), fminf(mb[6], mb[7]));
        float c = fminf(fminf(mb[8], mb[9]), fminf(mb[10], mb[11]));
        float d = fminf(fminf(mb[12], mb[13]), fminf(mb[14], mb[15]));
        float v = fminf(fminf(a, b), fminf(c, d));
        v = fminf(v, __shfl_xor(v, 32));
        if (half == 0) pout[32 + lid] = v;
    }
}

// Combine: min over the SSPLIT ref-splits per query, weighted sum into out.
__global__ __launch_bounds__(256) void nn_combine_kernel(
    const float* __restrict__ partial, const float* __restrict__ weight,
    float* __restrict__ out)
{
    const int b   = blockIdx.x;        // 0..127 : dir = b>>6, qc = b&63
    const int dir = b >> 6;
    const int qc  = b & 63;
    const int t   = threadIdx.x;

    const float* p = partial + ((size_t)((dir * QCH + qc) * SSPLIT)) * QBLK;
    float v = p[t];
#pragma unroll
    for (int s = 1; s < SSPLIT; ++s)
        v = fminf(v, p[(size_t)s * QBLK + t]);

    for (int off = 32; off; off >>= 1) v += __shfl_down(v, off);
    __shared__ float ws[4];
    if ((t & 63) == 0) ws[t >> 6] = v;
    __syncthreads();
    if (t == 0) {
        const float sum = ws[0] + ws[1] + ws[2] + ws[3];
        const float wgt = weight[0];
        const float scale = (dir ? (1.0f - wgt) : wgt) / (3.0f * (float)NPTS);
        atomicAdd(out, sum * scale);
    }
}

extern "C" void kernel_launch(void* const* d_in, const int* in_sizes, int n_in,
                              void* d_out, int out_size, void* d_ws, size_t ws_size,
                              hipStream_t stream) {
    const float* pred   = (const float*)d_in[0];
    const float* gt     = (const float*)d_in[1];
    const float* weight = (const float*)d_in[2];

    // ws: [partial 2 MB][aform 1 MB][bform 1 MB]
    float* partial = (float*)d_ws;                       // 2*QCH*SSPLIT*QBLK f32
    uint4* aform = (uint4*)((char*)d_ws + (size_t)2 * QCH * SSPLIT * QBLK * 4);
    uint4* bform = aform + (size_t)2 * NPTS * 2;

    prep_kernel<<<2 * NPTS / 256, 256, 0, stream>>>(pred, gt, aform, bform,
                                                    (float*)d_out);
    nn_part_kernel<<<NB1, 256, 0, stream>>>(aform, bform, partial);
    nn_combine_kernel<<<2 * QCH, 256, 0, stream>>>(partial, weight, (float*)d_out);
}